// Round 1
// baseline (991.847 us; speedup 1.0000x reference)
//
#include <hip/hip_runtime.h>

#define CH 32      // chunk length
#define DD 64      // dk = dv
#define NCHUNK 256 // chunks per (b,h)
#define SEQ 8192   // sequence length
#define BH 32      // b*h

// ---------------------------------------------------------------------------
// Kernel 1: per-chunk preprocessing. One block (256 thr) per chunk.
//  - l2-normalize q,k rows (written back in-place to d_in)
//  - T = (I + tril(kb @ kn^T, -1))^{-1} via forward substitution
//  - u = T @ (v*beta)  -> staged in d_out o-region
//  - w = T @ (k*beta)  -> ws
//  - P = tril(qn @ kn^T) incl diag -> ws
// ---------------------------------------------------------------------------
__global__ __launch_bounds__(256) void prep_kernel(
    float* __restrict__ q, float* __restrict__ k,
    const float* __restrict__ v, const float* __restrict__ beta,
    float* __restrict__ u_out, float* __restrict__ w_out, float* __restrict__ p_out)
{
    const int blk = blockIdx.x;
    const int bh = blk >> 8;
    const int cc = blk & 255;
    const size_t base = ((size_t)bh * SEQ + (size_t)cc * CH) * DD;
    const int t = threadIdx.x;

    __shared__ __align__(16) float qs[CH][68];
    __shared__ __align__(16) float ks[CH][68];
    __shared__ __align__(16) float kb[CH][68];
    __shared__ __align__(16) float vb[CH][68];
    __shared__ float A[CH][33];
    __shared__ float rowbuf[CH];
    __shared__ float bet[CH];
    __shared__ float rnq[CH];
    __shared__ float rnk[CH];

    if (t < CH) bet[t] = beta[(size_t)bh * SEQ + (size_t)cc * CH + t];
    for (int rep = 0; rep < 2; ++rep) {
        int idx = t + rep * 256;          // float4 index (512 total per array)
        int r = idx >> 4, d4 = idx & 15;
        float4 vq = *(const float4*)&q[base + (size_t)idx * 4];
        float4 vk = *(const float4*)&k[base + (size_t)idx * 4];
        float4 vv = *(const float4*)&v[base + (size_t)idx * 4];
        *(float4*)&qs[r][4 * d4] = vq;
        *(float4*)&ks[r][4 * d4] = vk;
        *(float4*)&vb[r][4 * d4] = vv;
    }
    __syncthreads();
    if (t < CH) {
        float ss = 0.f;
        for (int d4 = 0; d4 < 16; ++d4) {
            float4 x = *(const float4*)&qs[t][4 * d4];
            ss += x.x * x.x + x.y * x.y + x.z * x.z + x.w * x.w;
        }
        rnq[t] = rsqrtf(ss + 1e-6f);
    } else if (t < 2 * CH) {
        int r = t - CH;
        float ss = 0.f;
        for (int d4 = 0; d4 < 16; ++d4) {
            float4 x = *(const float4*)&ks[r][4 * d4];
            ss += x.x * x.x + x.y * x.y + x.z * x.z + x.w * x.w;
        }
        rnk[r] = rsqrtf(ss + 1e-6f);
    }
    __syncthreads();
    for (int rep = 0; rep < 2; ++rep) {
        int idx = t + rep * 256;
        int r = idx >> 4, d4 = idx & 15;
        float4 vq = *(const float4*)&qs[r][4 * d4];
        float4 vk = *(const float4*)&ks[r][4 * d4];
        float4 vv = *(const float4*)&vb[r][4 * d4];
        float fq = rnq[r], fk = rnk[r], fb = bet[r];
        vq.x *= fq; vq.y *= fq; vq.z *= fq; vq.w *= fq;
        vk.x *= fk; vk.y *= fk; vk.z *= fk; vk.w *= fk;
        float4 vkb = make_float4(vk.x * fb, vk.y * fb, vk.z * fb, vk.w * fb);
        float4 vvb = make_float4(vv.x * fb, vv.y * fb, vv.z * fb, vv.w * fb);
        *(float4*)&qs[r][4 * d4] = vq;
        *(float4*)&ks[r][4 * d4] = vk;
        *(float4*)&kb[r][4 * d4] = vkb;
        *(float4*)&vb[r][4 * d4] = vvb;
        *(float4*)&q[base + (size_t)idx * 4] = vq;   // write normalized back in-place
        *(float4*)&k[base + (size_t)idx * 4] = vk;
    }
    __syncthreads();
    // A[i][j] = -(kb_i . kn_j) for j<i, else 0
    for (int rep = 0; rep < 4; ++rep) {
        int idx = t + rep * 256;
        int i = idx >> 5, j = idx & 31;
        float s = 0.f;
        if (j < i) {
            for (int d4 = 0; d4 < 16; ++d4) {
                float4 a = *(const float4*)&kb[i][4 * d4];
                float4 b = *(const float4*)&ks[j][4 * d4];
                s += a.x * b.x + a.y * b.y + a.z * b.z + a.w * b.w;
            }
            s = -s;
        }
        A[i][j] = s;
    }
    __syncthreads();
    // forward substitution: A <- (I - A)^{-1} - I  (strictly lower)
    for (int i = 1; i < CH; ++i) {
        if (t < CH) rowbuf[t] = A[i][t];
        __syncthreads();
        if (t < i) {
            float s = 0.f;
            for (int j = 1; j < i; ++j) s += rowbuf[j] * A[j][t];  // A[j][t]=0 for j<=t
            A[i][t] += s;
        }
        __syncthreads();
    }
    // u = (A+I)@vb ; w = (A+I)@kb
    for (int rep = 0; rep < 2; ++rep) {
        int idx = t + rep * 256;
        int i = idx >> 4, d4 = idx & 15;
        float4 su = *(const float4*)&vb[i][4 * d4];
        float4 sw = *(const float4*)&kb[i][4 * d4];
        for (int j = 0; j < i; ++j) {
            float a = A[i][j];
            float4 vvj = *(const float4*)&vb[j][4 * d4];
            float4 vkj = *(const float4*)&kb[j][4 * d4];
            su.x += a * vvj.x; su.y += a * vvj.y; su.z += a * vvj.z; su.w += a * vvj.w;
            sw.x += a * vkj.x; sw.y += a * vkj.y; sw.z += a * vkj.z; sw.w += a * vkj.w;
        }
        *(float4*)&u_out[base + (size_t)idx * 4] = su;
        *(float4*)&w_out[base + (size_t)idx * 4] = sw;
    }
    // P[i][j] = (j<=i) ? qn_i . kn_j : 0
    {
        const size_t pbase = ((size_t)bh * NCHUNK + cc) * (CH * CH);
        int i = t >> 3, j4 = t & 7;
        float res[4];
        for (int jj = 0; jj < 4; ++jj) {
            int j = 4 * j4 + jj;
            float s = 0.f;
            for (int d4 = 0; d4 < 16; ++d4) {
                float4 a = *(const float4*)&qs[i][4 * d4];
                float4 b = *(const float4*)&ks[j][4 * d4];
                s += a.x * b.x + a.y * b.y + a.z * b.z + a.w * b.w;
            }
            res[jj] = (j <= i) ? s : 0.f;
        }
        *(float4*)&p_out[pbase + (size_t)t * 4] =
            make_float4(res[0], res[1], res[2], res[3]);
    }
}

// ---------------------------------------------------------------------------
// Kernel 2: sequential chunk scan. 256 blocks = 32 (b,h) x 8 column-groups of
// dv (columns decouple in the recurrence). Each block carries S[64][8] in LDS
// across 256 chunks. u staged in the d_out o-region is read, then overwritten
// with o at identical addresses by the same block (read-before-write).
// ---------------------------------------------------------------------------
__global__ __launch_bounds__(256) void scan_kernel(
    const float* __restrict__ q, const float* __restrict__ k,
    const float* __restrict__ w_in, const float* __restrict__ p_in,
    float* __restrict__ uo, float* __restrict__ s_out)
{
    const int bh = blockIdx.x & 31;
    const int g  = blockIdx.x >> 5;      // column group (8 cols)
    const int t  = threadIdx.x;

    __shared__ __align__(16) float qs[CH][68];
    __shared__ __align__(16) float ws2[CH][68];
    __shared__ __align__(16) float kt[DD][36];   // k transposed: kt[d][r]
    __shared__ __align__(16) float Ps[CH][36];
    __shared__ __align__(16) float ut[8][36];    // u columns: ut[c8][r]
    __shared__ __align__(16) float St[8][68];    // S transposed: St[c8][d]
    __shared__ float os[CH][9];

    for (int idx = t; idx < 8 * 68; idx += 256) ((float*)St)[idx] = 0.f;

    float4 vq0, vq1, vw0, vw1, vk0, vk1, vp;
    float vu;
    // preload chunk 0
    {
        size_t cb = ((size_t)bh * SEQ) * DD;
        vq0 = *(const float4*)&q[cb + (size_t)t * 4];
        vq1 = *(const float4*)&q[cb + (size_t)(t + 256) * 4];
        vw0 = *(const float4*)&w_in[cb + (size_t)t * 4];
        vw1 = *(const float4*)&w_in[cb + (size_t)(t + 256) * 4];
        vk0 = *(const float4*)&k[cb + (size_t)t * 4];
        vk1 = *(const float4*)&k[cb + (size_t)(t + 256) * 4];
        vp  = *(const float4*)&p_in[((size_t)bh * NCHUNK) * 1024 + (size_t)t * 4];
        vu  = uo[cb + (size_t)(t >> 3) * DD + (size_t)g * 8 + (t & 7)];
    }

    for (int c = 0; c < NCHUNK; ++c) {
        // stage regs -> LDS
        {
            int r = t >> 4, dq = t & 15;
            *(float4*)&qs[r][4 * dq] = vq0;
            *(float4*)&ws2[r][4 * dq] = vw0;
            kt[4 * dq + 0][r] = vk0.x; kt[4 * dq + 1][r] = vk0.y;
            kt[4 * dq + 2][r] = vk0.z; kt[4 * dq + 3][r] = vk0.w;
            int idx = t + 256;
            int r2 = idx >> 4, dq2 = idx & 15;
            *(float4*)&qs[r2][4 * dq2] = vq1;
            *(float4*)&ws2[r2][4 * dq2] = vw1;
            kt[4 * dq2 + 0][r2] = vk1.x; kt[4 * dq2 + 1][r2] = vk1.y;
            kt[4 * dq2 + 2][r2] = vk1.z; kt[4 * dq2 + 3][r2] = vk1.w;
            *(float4*)&Ps[t >> 3][4 * (t & 7)] = vp;
            ut[t & 7][t >> 3] = vu;
        }
        __syncthreads();  // A
        // prefetch next chunk into regs (hides HBM/L2 latency behind compute)
        {
            int cn = (c + 1 < NCHUNK) ? c + 1 : c;
            size_t cb = ((size_t)bh * SEQ + (size_t)cn * CH) * DD;
            vq0 = *(const float4*)&q[cb + (size_t)t * 4];
            vq1 = *(const float4*)&q[cb + (size_t)(t + 256) * 4];
            vw0 = *(const float4*)&w_in[cb + (size_t)t * 4];
            vw1 = *(const float4*)&w_in[cb + (size_t)(t + 256) * 4];
            vk0 = *(const float4*)&k[cb + (size_t)t * 4];
            vk1 = *(const float4*)&k[cb + (size_t)(t + 256) * 4];
            vp  = *(const float4*)&p_in[((size_t)bh * NCHUNK + cn) * 1024 + (size_t)t * 4];
            vu  = uo[cb + (size_t)(t >> 3) * DD + (size_t)g * 8 + (t & 7)];
        }
        // u_i = u0 - w @ S ; partial o = q @ S   (reads old S)
        const int c8 = t >> 5, r = t & 31;
        float accu = ut[c8][r];
        float acco = 0.f;
        for (int dq = 0; dq < 16; ++dq) {
            float4 sv = *(const float4*)&St[c8][4 * dq];
            float4 wv = *(const float4*)&ws2[r][4 * dq];
            float4 qv = *(const float4*)&qs[r][4 * dq];
            accu -= wv.x * sv.x + wv.y * sv.y + wv.z * sv.z + wv.w * sv.w;
            acco += qv.x * sv.x + qv.y * sv.y + qv.z * sv.z + qv.w * sv.w;
        }
        ut[c8][r] = accu;   // own element: no cross-thread hazard before sync
        __syncthreads();  // B
        // o += P @ u_i
        for (int jq = 0; jq < 8; ++jq) {
            float4 pv = *(const float4*)&Ps[r][4 * jq];
            float4 uv = *(const float4*)&ut[c8][4 * jq];
            acco += pv.x * uv.x + pv.y * uv.y + pv.z * uv.z + pv.w * uv.w;
        }
        os[r][c8] = acco;
        __syncthreads();  // C
        // coalesced o store (overwrites the u slice this block already consumed)
        {
            size_t ob = ((size_t)bh * SEQ + (size_t)c * CH) * DD + (size_t)g * 8;
            int r2 = t >> 3, c2 = t & 7;
            uo[ob + (size_t)r2 * DD + c2] = os[r2][c2];
        }
        // S += k^T @ u_i
        {
            int c8b = t >> 5, d0 = t & 31;
            float a0 = 0.f, a1 = 0.f;
            for (int rq = 0; rq < 8; ++rq) {
                float4 uv = *(const float4*)&ut[c8b][4 * rq];
                float4 k0 = *(const float4*)&kt[d0][4 * rq];
                float4 k1 = *(const float4*)&kt[d0 + 32][4 * rq];
                a0 += k0.x * uv.x + k0.y * uv.y + k0.z * uv.z + k0.w * uv.w;
                a1 += k1.x * uv.x + k1.y * uv.y + k1.z * uv.z + k1.w * uv.w;
            }
            St[c8b][d0] += a0;
            St[c8b][d0 + 32] += a1;
        }
        __syncthreads();  // D
    }
    // final S -> d_out (shape b,h,dk,dv)
    for (int rep = 0; rep < 2; ++rep) {
        int idx = t + rep * 256;
        int d = idx >> 3, c8 = idx & 7;
        s_out[(size_t)bh * (DD * DD) + (size_t)d * DD + (size_t)g * 8 + c8] = St[c8][d];
    }
}

extern "C" void kernel_launch(void* const* d_in, const int* in_sizes, int n_in,
                              void* d_out, int out_size, void* d_ws, size_t ws_size,
                              hipStream_t stream) {
    float* q = (float*)d_in[0];
    float* k = (float*)d_in[1];
    const float* v = (const float*)d_in[2];
    const float* beta = (const float*)d_in[3];
    float* out = (float*)d_out;
    float* o_region = out;                          // 16,777,216 floats (also u staging)
    float* s_region = out + (size_t)BH * SEQ * DD;  // 131,072 floats
    float* wsf = (float*)d_ws;
    float* w_buf = wsf;                             // 16,777,216 floats
    float* p_buf = wsf + (size_t)BH * SEQ * DD;     // 8,388,608 floats (total ws: 96MB)

    prep_kernel<<<BH * NCHUNK, 256, 0, stream>>>(q, k, v, beta, o_region, w_buf, p_buf);
    scan_kernel<<<256, 256, 0, stream>>>(q, k, w_buf, p_buf, o_region, s_region);
}

// Round 2
// 865.470 us; speedup vs baseline: 1.1460x; 1.1460x over previous
//
#include <hip/hip_runtime.h>

#define CH 32      // chunk length
#define DD 64      // dk = dv
#define NCHUNK 256 // chunks per (b,h)
#define SEQ 8192   // sequence length
#define BH 32      // b*h

// ---------------------------------------------------------------------------
// Kernel 1: per-chunk preprocessing. One block (256 thr) per chunk.
//  - l2-normalize q,k rows (written back in-place to d_in)
//  - A = -strict_tril(kb @ kn^T)  and  P = tril(qn @ kn^T) in ONE merged pass
//  - forward substitution (T = (I-A)^-1 - I) done by a single wave,
//    columns held in registers, zero barriers inside
//  - u = (A+I) @ (v*beta) -> staged in d_out o-region ; w = (A+I) @ k_beta -> ws
// ---------------------------------------------------------------------------
__global__ __launch_bounds__(256) void prep_kernel(
    float* __restrict__ q, float* __restrict__ k,
    const float* __restrict__ v, const float* __restrict__ beta,
    float* __restrict__ u_out, float* __restrict__ w_out, float* __restrict__ p_out)
{
    const int blk = blockIdx.x;
    const int bh = blk >> 8;
    const int cc = blk & 255;
    const size_t base = ((size_t)bh * SEQ + (size_t)cc * CH) * DD;
    const int t = threadIdx.x;

    __shared__ __align__(16) float qs[CH][68];
    __shared__ __align__(16) float ks[CH][68];
    __shared__ __align__(16) float kb[CH][68];
    __shared__ __align__(16) float vb[CH][68];
    __shared__ float A[CH][33];
    __shared__ float bet[CH];
    __shared__ float rnq[CH];
    __shared__ float rnk[CH];

    if (t < CH) bet[t] = beta[(size_t)bh * SEQ + (size_t)cc * CH + t];
    for (int rep = 0; rep < 2; ++rep) {
        int idx = t + rep * 256;          // float4 index (512 total per array)
        int r = idx >> 4, d4 = idx & 15;
        float4 vq = *(const float4*)&q[base + (size_t)idx * 4];
        float4 vk = *(const float4*)&k[base + (size_t)idx * 4];
        float4 vv = *(const float4*)&v[base + (size_t)idx * 4];
        *(float4*)&qs[r][4 * d4] = vq;
        *(float4*)&ks[r][4 * d4] = vk;
        *(float4*)&vb[r][4 * d4] = vv;
    }
    __syncthreads();
    if (t < CH) {
        float ss = 0.f;
        for (int d4 = 0; d4 < 16; ++d4) {
            float4 x = *(const float4*)&qs[t][4 * d4];
            ss += x.x * x.x + x.y * x.y + x.z * x.z + x.w * x.w;
        }
        rnq[t] = rsqrtf(ss + 1e-6f);
    } else if (t < 2 * CH) {
        int r = t - CH;
        float ss = 0.f;
        for (int d4 = 0; d4 < 16; ++d4) {
            float4 x = *(const float4*)&ks[r][4 * d4];
            ss += x.x * x.x + x.y * x.y + x.z * x.z + x.w * x.w;
        }
        rnk[r] = rsqrtf(ss + 1e-6f);
    }
    __syncthreads();
    for (int rep = 0; rep < 2; ++rep) {
        int idx = t + rep * 256;
        int r = idx >> 4, d4 = idx & 15;
        float4 vq = *(const float4*)&qs[r][4 * d4];
        float4 vk = *(const float4*)&ks[r][4 * d4];
        float4 vv = *(const float4*)&vb[r][4 * d4];
        float fq = rnq[r], fk = rnk[r], fb = bet[r];
        vq.x *= fq; vq.y *= fq; vq.z *= fq; vq.w *= fq;
        vk.x *= fk; vk.y *= fk; vk.z *= fk; vk.w *= fk;
        float4 vkb = make_float4(vk.x * fb, vk.y * fb, vk.z * fb, vk.w * fb);
        float4 vvb = make_float4(vv.x * fb, vv.y * fb, vv.z * fb, vv.w * fb);
        *(float4*)&qs[r][4 * d4] = vq;
        *(float4*)&ks[r][4 * d4] = vk;
        *(float4*)&kb[r][4 * d4] = vkb;
        *(float4*)&vb[r][4 * d4] = vvb;
        *(float4*)&q[base + (size_t)idx * 4] = vq;   // write normalized back in-place
        *(float4*)&k[base + (size_t)idx * 4] = vk;
    }
    __syncthreads();
    // merged: A[i][j] = -(kb_i . kn_j) (j<i), P[i][j] = qn_i . kn_j (j<=i)
    {
        const size_t pbase = ((size_t)bh * NCHUNK + cc) * (CH * CH);
        for (int rep = 0; rep < 4; ++rep) {
            int idx = t + rep * 256;
            int i = idx >> 5, j = idx & 31;
            float sa = 0.f, sp = 0.f;
            if (j <= i) {
                for (int d4 = 0; d4 < 16; ++d4) {
                    float4 kk = *(const float4*)&ks[j][4 * d4];
                    float4 qq = *(const float4*)&qs[i][4 * d4];
                    float4 bb = *(const float4*)&kb[i][4 * d4];
                    sp += qq.x * kk.x + qq.y * kk.y + qq.z * kk.z + qq.w * kk.w;
                    sa += bb.x * kk.x + bb.y * kk.y + bb.z * kk.z + bb.w * kk.w;
                }
            }
            A[i][j] = (j < i) ? -sa : 0.f;
            p_out[pbase + idx] = (j <= i) ? sp : 0.f;
        }
    }
    __syncthreads();
    // forward substitution, single wave, columns in registers, no barriers.
    // A[i][col] += sum_{j<i} Aorig[i][j] * A[j][col]  (A in LDS stays ORIGINAL
    // during the loop; updated columns live in creg[]; written back at end)
    if (t < 64) {
        const int col = t & 31;
        float creg[CH];
        #pragma unroll
        for (int j = 0; j < CH; ++j) creg[j] = A[j][col];
        #pragma unroll
        for (int i = 1; i < CH; ++i) {
            float s = 0.f;
            #pragma unroll
            for (int j = 1; j < i; ++j) s += A[i][j] * creg[j];
            if (col < i) creg[i] += s;
        }
        if (t < 32) {
            #pragma unroll
            for (int j = 0; j < CH; ++j) A[j][col] = creg[j];
        }
    }
    __syncthreads();
    // u = (A+I)@vb ; w = (A+I)@kb   -- 4 rows per thread, threads 0..127
    if (t < 128) {
        const int d4 = t & 15;
        const int i0 = (t >> 4) * 4;
        float4 su[4], sw[4];
        #pragma unroll
        for (int ii = 0; ii < 4; ++ii) {
            su[ii] = *(const float4*)&vb[i0 + ii][4 * d4];
            sw[ii] = *(const float4*)&kb[i0 + ii][4 * d4];
        }
        for (int j = 0; j <= i0 + 2; ++j) {
            float4 vv = *(const float4*)&vb[j][4 * d4];
            float4 vk = *(const float4*)&kb[j][4 * d4];
            #pragma unroll
            for (int ii = 0; ii < 4; ++ii) {
                float a = (j < i0 + ii) ? A[i0 + ii][j] : 0.f;
                su[ii].x += a * vv.x; su[ii].y += a * vv.y;
                su[ii].z += a * vv.z; su[ii].w += a * vv.w;
                sw[ii].x += a * vk.x; sw[ii].y += a * vk.y;
                sw[ii].z += a * vk.z; sw[ii].w += a * vk.w;
            }
        }
        #pragma unroll
        for (int ii = 0; ii < 4; ++ii) {
            *(float4*)&u_out[base + (size_t)(i0 + ii) * DD + 4 * d4] = su[ii];
            *(float4*)&w_out[base + (size_t)(i0 + ii) * DD + 4 * d4] = sw[ii];
        }
    }
}

// ---------------------------------------------------------------------------
// Kernel 2: sequential chunk scan. 256 blocks = 32 (b,h) x 8 column-groups.
// Register-tiled phases, XOR-swizzled LDS slots (conflict-free), 4 barriers.
// u staged in the d_out o-region is read (prefetch of chunk c in iter c-1),
// then overwritten with o by the same block.
// ---------------------------------------------------------------------------
__global__ __launch_bounds__(256) void scan_kernel(
    const float* __restrict__ q, const float* __restrict__ k,
    const float* __restrict__ w_in, const float* __restrict__ p_in,
    float* __restrict__ uo, float* __restrict__ s_out)
{
    const int bh = blockIdx.x & 31;
    const int g  = blockIdx.x >> 5;      // column group (8 cols of dv)
    const int t  = threadIdx.x;

    // row-major with 16 float4 slots per row, physical slot = dq ^ ((r>>1)&15)
    __shared__ __align__(16) float qs[32 * 64];
    __shared__ __align__(16) float ws[32 * 64];
    __shared__ __align__(16) float ks[32 * 64];
    // P: 8 float4 slots/row, phys = jq ^ ((r>>1)&7), row stride 36
    __shared__ __align__(16) float Ps[32 * 36];
    // u columns: ut[c][r], 8 slots over r, phys = (rq + 2c)&7, stride 36
    __shared__ __align__(16) float ut[8 * 36];
    // S columns: St[c][d], stride 68 (reads broadcast / writes 2-way: free)
    __shared__ __align__(16) float St[8 * 68];
    __shared__ __align__(16) float pr[64 * 12];  // phase1 K-split partials

    for (int idx = t; idx < 8 * 68; idx += 256) St[idx] = 0.f;

    float4 vq0, vq1, vw0, vw1, vk0, vk1, vp;
    float vu;
    {   // preload chunk 0
        size_t cb = ((size_t)bh * SEQ) * DD;
        vq0 = *(const float4*)&q[cb + (size_t)t * 4];
        vq1 = *(const float4*)&q[cb + (size_t)(t + 256) * 4];
        vw0 = *(const float4*)&w_in[cb + (size_t)t * 4];
        vw1 = *(const float4*)&w_in[cb + (size_t)(t + 256) * 4];
        vk0 = *(const float4*)&k[cb + (size_t)t * 4];
        vk1 = *(const float4*)&k[cb + (size_t)(t + 256) * 4];
        vp  = *(const float4*)&p_in[((size_t)bh * NCHUNK) * 1024 + (size_t)t * 4];
        vu  = uo[cb + (size_t)(t >> 3) * DD + (size_t)g * 8 + (t & 7)];
    }

    const int m  = t & 15;          // phase1/2 lane coords (threads 0..127)
    const int cg = (t >> 4) & 3;
    const int r0 = 2 * m, c0 = 2 * cg;

    for (int c = 0; c < NCHUNK; ++c) {
        // ---- stage regs -> LDS (swizzled) ----
        {
            int r = t >> 4, dq = t & 15;
            *(float4*)&qs[r * 64 + 4 * ((dq ^ ((r >> 1) & 15)))] = vq0;
            *(float4*)&ws[r * 64 + 4 * ((dq ^ ((r >> 1) & 15)))] = vw0;
            *(float4*)&ks[r * 64 + 4 * ((dq ^ ((r >> 1) & 15)))] = vk0;
            int r2 = r + 16;
            *(float4*)&qs[r2 * 64 + 4 * ((dq ^ ((r2 >> 1) & 15)))] = vq1;
            *(float4*)&ws[r2 * 64 + 4 * ((dq ^ ((r2 >> 1) & 15)))] = vw1;
            *(float4*)&ks[r2 * 64 + 4 * ((dq ^ ((r2 >> 1) & 15)))] = vk1;
            int rp = t >> 3, jq = t & 7;
            *(float4*)&Ps[rp * 36 + 4 * (jq ^ ((rp >> 1) & 7))] = vp;
            ut[(t & 7) * 36 + 4 * ((((t >> 3) >> 2) + 2 * (t & 7)) & 7) + ((t >> 3) & 3)] = vu;
        }
        __syncthreads();  // A
        // ---- prefetch next chunk into regs ----
        {
            int cn = (c + 1 < NCHUNK) ? c + 1 : c;
            size_t cb = ((size_t)bh * SEQ + (size_t)cn * CH) * DD;
            vq0 = *(const float4*)&q[cb + (size_t)t * 4];
            vq1 = *(const float4*)&q[cb + (size_t)(t + 256) * 4];
            vw0 = *(const float4*)&w_in[cb + (size_t)t * 4];
            vw1 = *(const float4*)&w_in[cb + (size_t)(t + 256) * 4];
            vk0 = *(const float4*)&k[cb + (size_t)t * 4];
            vk1 = *(const float4*)&k[cb + (size_t)(t + 256) * 4];
            vp  = *(const float4*)&p_in[((size_t)bh * NCHUNK + cn) * 1024 + (size_t)t * 4];
            vu  = uo[cb + (size_t)(t >> 3) * DD + (size_t)g * 8 + (t & 7)];
        }
        // ---- phase1: (w@S) and (q@S), 2r x 2c tiles, K split across 2 waves
        float pu00 = 0.f, pu01 = 0.f, pu10 = 0.f, pu11 = 0.f;
        float po00 = 0.f, po01 = 0.f, po10 = 0.f, po11 = 0.f;
        if (t < 128) {
            const int kh = t >> 6;
            for (int dq = kh * 8; dq < kh * 8 + 8; ++dq) {
                int sl = 4 * (dq ^ m);   // (r0>>1)&15 == m for both rows
                float4 w0 = *(const float4*)&ws[r0 * 64 + sl];
                float4 w1 = *(const float4*)&ws[(r0 + 1) * 64 + sl];
                float4 q0 = *(const float4*)&qs[r0 * 64 + sl];
                float4 q1 = *(const float4*)&qs[(r0 + 1) * 64 + sl];
                float4 s0 = *(const float4*)&St[c0 * 68 + 4 * dq];
                float4 s1 = *(const float4*)&St[(c0 + 1) * 68 + 4 * dq];
                pu00 += w0.x * s0.x + w0.y * s0.y + w0.z * s0.z + w0.w * s0.w;
                pu01 += w0.x * s1.x + w0.y * s1.y + w0.z * s1.z + w0.w * s1.w;
                pu10 += w1.x * s0.x + w1.y * s0.y + w1.z * s0.z + w1.w * s0.w;
                pu11 += w1.x * s1.x + w1.y * s1.y + w1.z * s1.z + w1.w * s1.w;
                po00 += q0.x * s0.x + q0.y * s0.y + q0.z * s0.z + q0.w * s0.w;
                po01 += q0.x * s1.x + q0.y * s1.y + q0.z * s1.z + q0.w * s1.w;
                po10 += q1.x * s0.x + q1.y * s0.y + q1.z * s0.z + q1.w * s0.w;
                po11 += q1.x * s1.x + q1.y * s1.y + q1.z * s1.z + q1.w * s1.w;
            }
            if (kh) {
                int tid = t & 63;
                *(float4*)&pr[tid * 12 + 0] = make_float4(pu00, pu01, pu10, pu11);
                *(float4*)&pr[tid * 12 + 4] = make_float4(po00, po01, po10, po11);
            }
        }
        __syncthreads();  // B
        // ---- combine partials, finalize u, write ut (threads 0..63) ----
        if (t < 64) {
            float4 fu = *(const float4*)&pr[t * 12 + 0];
            float4 fo = *(const float4*)&pr[t * 12 + 4];
            po00 += fo.x; po01 += fo.y; po10 += fo.z; po11 += fo.w;
            // addr of u element (r,c): c*36 + 4*((r>>2 + 2c)&7) + (r&3)
            #define UADDR(r, cc2) ((cc2) * 36 + 4 * ((((r) >> 2) + 2 * (cc2)) & 7) + ((r) & 3))
            float u00 = ut[UADDR(r0, c0)]     - pu00 - fu.x;
            float u01 = ut[UADDR(r0, c0 + 1)] - pu01 - fu.y;
            float u10 = ut[UADDR(r0 + 1, c0)]     - pu10 - fu.z;
            float u11 = ut[UADDR(r0 + 1, c0 + 1)] - pu11 - fu.w;
            ut[UADDR(r0, c0)]         = u00;
            ut[UADDR(r0, c0 + 1)]     = u01;
            ut[UADDR(r0 + 1, c0)]     = u10;
            ut[UADDR(r0 + 1, c0 + 1)] = u11;
        }
        __syncthreads();  // C
        if (t < 64) {
            // ---- phase2: o += P @ u (same cells as phase1) ----
            for (int jq = 0; jq < 8; ++jq) {
                int slp = 4 * (jq ^ (m & 7));
                float4 p0 = *(const float4*)&Ps[r0 * 36 + slp];
                float4 p1 = *(const float4*)&Ps[(r0 + 1) * 36 + slp];
                float4 ua = *(const float4*)&ut[c0 * 36 + 4 * ((jq + 2 * c0) & 7)];
                float4 ub = *(const float4*)&ut[(c0 + 1) * 36 + 4 * ((jq + 2 * (c0 + 1)) & 7)];
                po00 += p0.x * ua.x + p0.y * ua.y + p0.z * ua.z + p0.w * ua.w;
                po01 += p0.x * ub.x + p0.y * ub.y + p0.z * ub.z + p0.w * ub.w;
                po10 += p1.x * ua.x + p1.y * ua.y + p1.z * ua.z + p1.w * ua.w;
                po11 += p1.x * ub.x + p1.y * ub.y + p1.z * ub.z + p1.w * ub.w;
            }
            size_t ob = ((size_t)bh * SEQ + (size_t)c * CH) * DD + (size_t)g * 8;
            uo[ob + (size_t)r0 * DD + c0]           = po00;
            uo[ob + (size_t)r0 * DD + c0 + 1]       = po01;
            uo[ob + (size_t)(r0 + 1) * DD + c0]     = po10;
            uo[ob + (size_t)(r0 + 1) * DD + c0 + 1] = po11;
        } else if (t >= 128) {
            // ---- phase3: S[d][c] += sum_r k[r][d] * u[r][c] ----
            const int tid = t - 128;
            const int d0 = tid & 31, d1 = d0 + 32;
            const int ca = tid >> 5, cb2 = ca + 4;
            float s00 = 0.f, s01 = 0.f, s10 = 0.f, s11 = 0.f;
            for (int rq = 0; rq < 8; ++rq) {
                float4 ua = *(const float4*)&ut[ca * 36 + 4 * ((rq + 2 * ca) & 7)];
                float4 ub = *(const float4*)&ut[cb2 * 36 + 4 * ((rq + 2 * cb2) & 7)];
                #pragma unroll
                for (int j = 0; j < 4; ++j) {
                    int r = 4 * rq + j;
                    int rsw = (r >> 1) & 15;
                    float k0 = ks[r * 64 + 4 * (((d0 >> 2) ^ rsw)) + (d0 & 3)];
                    float k1 = ks[r * 64 + 4 * (((d1 >> 2) ^ rsw)) + (d1 & 3)];
                    float uaj = (j == 0) ? ua.x : (j == 1) ? ua.y : (j == 2) ? ua.z : ua.w;
                    float ubj = (j == 0) ? ub.x : (j == 1) ? ub.y : (j == 2) ? ub.z : ub.w;
                    s00 += k0 * uaj; s01 += k0 * ubj;
                    s10 += k1 * uaj; s11 += k1 * ubj;
                }
            }
            St[ca * 68 + d0]  += s00;
            St[cb2 * 68 + d0] += s01;
            St[ca * 68 + d1]  += s10;
            St[cb2 * 68 + d1] += s11;
        }
        __syncthreads();  // D
    }
    // final S -> d_out (shape b,h,dk,dv)
    for (int rep = 0; rep < 2; ++rep) {
        int idx = t + rep * 256;
        int d = idx >> 3, c8 = idx & 7;
        s_out[(size_t)bh * (DD * DD) + (size_t)d * DD + (size_t)g * 8 + c8] = St[c8 * 68 + d];
    }
}

extern "C" void kernel_launch(void* const* d_in, const int* in_sizes, int n_in,
                              void* d_out, int out_size, void* d_ws, size_t ws_size,
                              hipStream_t stream) {
    float* q = (float*)d_in[0];
    float* k = (float*)d_in[1];
    const float* v = (const float*)d_in[2];
    const float* beta = (const float*)d_in[3];
    float* out = (float*)d_out;
    float* o_region = out;                          // 16,777,216 floats (also u staging)
    float* s_region = out + (size_t)BH * SEQ * DD;  // 131,072 floats
    float* wsf = (float*)d_ws;
    float* w_buf = wsf;                             // 16,777,216 floats
    float* p_buf = wsf + (size_t)BH * SEQ * DD;     // 8,388,608 floats (total ws: 96MB)

    prep_kernel<<<BH * NCHUNK, 256, 0, stream>>>(q, k, v, beta, o_region, w_buf, p_buf);
    scan_kernel<<<256, 256, 0, stream>>>(q, k, w_buf, p_buf, o_region, s_region);
}

// Round 3
// 608.732 us; speedup vs baseline: 1.6294x; 1.4218x over previous
//
#include <hip/hip_runtime.h>

#define CH 32      // chunk length
#define DD 64      // dk = dv
#define NCHUNK 256 // chunks per (b,h)
#define SEQ 8192   // sequence length
#define BH 32      // b*h

typedef _Float16 half8 __attribute__((ext_vector_type(8)));
typedef float f32x4 __attribute__((ext_vector_type(4)));
typedef unsigned short u16;

#define MFMA16(a, b, c) __builtin_amdgcn_mfma_f32_16x16x32_f16((a), (b), (c), 0, 0, 0)

// split fp32 -> f16 hi + f16 lo (hi+lo reconstructs to ~2^-21 rel), store frag
__device__ __forceinline__ void split_store(const float* src8, bool neg, u16* dst) {
    half8 hi, lo;
#pragma unroll
    for (int j = 0; j < 8; ++j) {
        float x = neg ? -src8[j] : src8[j];
        _Float16 xh = (_Float16)x;
        hi[j] = xh;
        lo[j] = (_Float16)(x - (float)xh);
    }
    *(half8*)dst = hi;
    *(half8*)(dst + 8) = lo;
}

__device__ __forceinline__ void hi_store(const float* src8, u16* dst) {
    half8 hi;
#pragma unroll
    for (int j = 0; j < 8; ++j) hi[j] = (_Float16)src8[j];
    *(half8*)dst = hi;
}

// ---------------------------------------------------------------------------
// Kernel 1: per-chunk preprocessing. One block (256 thr) per chunk.
// Outputs (all MFMA-frag-packed f16 except u0):
//   d_in[0] (over q): -w as A-frags, f16 hi/lo   [tile tw=mt*2+kt][lane][hi8|lo8]
//   d_in[1] (over k): k^T as A-frags, f16 hi/lo  [tile mt(d)][lane][hi8|lo8]
//   ws     : q-hi A-frags (32MB) + P-hi A-frags (16MB)
//   d_out o-region: u0 fp32 row-major (staging; overwritten with o by scan)
// A-frag layout (16x16x32): lane l supplies A[m=l&15][k=(l>>4)*8+j], j=0..7.
// ---------------------------------------------------------------------------
__global__ __launch_bounds__(256) void prep_kernel(
    float* __restrict__ q, float* __restrict__ k,
    const float* __restrict__ v, const float* __restrict__ beta,
    float* __restrict__ u_out, u16* __restrict__ qfrag, u16* __restrict__ pfrag)
{
    const int blk = blockIdx.x;
    const int bh = blk >> 8;
    const int cc = blk & 255;
    const size_t base = ((size_t)bh * SEQ + (size_t)cc * CH) * DD;
    const int t = threadIdx.x;

    __shared__ __align__(16) float qs[CH][68];
    __shared__ __align__(16) float ks[CH][68];
    __shared__ __align__(16) float kb[CH][68];
    __shared__ __align__(16) float vb[CH][68];
    __shared__ __align__(16) float wl[CH][68];
    __shared__ float A[CH][33];
    __shared__ __align__(16) float Pl[CH][36];
    __shared__ float bet[CH];
    __shared__ float rnq[CH];
    __shared__ float rnk[CH];

    if (t < CH) bet[t] = beta[(size_t)bh * SEQ + (size_t)cc * CH + t];
    for (int rep = 0; rep < 2; ++rep) {
        int idx = t + rep * 256;          // float4 index (512 total per array)
        int r = idx >> 4, d4 = idx & 15;
        float4 vq = *(const float4*)&q[base + (size_t)idx * 4];
        float4 vk = *(const float4*)&k[base + (size_t)idx * 4];
        float4 vv = *(const float4*)&v[base + (size_t)idx * 4];
        *(float4*)&qs[r][4 * d4] = vq;
        *(float4*)&ks[r][4 * d4] = vk;
        *(float4*)&vb[r][4 * d4] = vv;
    }
    __syncthreads();
    if (t < CH) {
        float ss = 0.f;
        for (int d4 = 0; d4 < 16; ++d4) {
            float4 x = *(const float4*)&qs[t][4 * d4];
            ss += x.x * x.x + x.y * x.y + x.z * x.z + x.w * x.w;
        }
        rnq[t] = rsqrtf(ss + 1e-6f);
    } else if (t < 2 * CH) {
        int r = t - CH;
        float ss = 0.f;
        for (int d4 = 0; d4 < 16; ++d4) {
            float4 x = *(const float4*)&ks[r][4 * d4];
            ss += x.x * x.x + x.y * x.y + x.z * x.z + x.w * x.w;
        }
        rnk[r] = rsqrtf(ss + 1e-6f);
    }
    __syncthreads();
    for (int rep = 0; rep < 2; ++rep) {
        int idx = t + rep * 256;
        int r = idx >> 4, d4 = idx & 15;
        float4 vq = *(const float4*)&qs[r][4 * d4];
        float4 vk = *(const float4*)&ks[r][4 * d4];
        float4 vv = *(const float4*)&vb[r][4 * d4];
        float fq = rnq[r], fk = rnk[r], fb = bet[r];
        vq.x *= fq; vq.y *= fq; vq.z *= fq; vq.w *= fq;
        vk.x *= fk; vk.y *= fk; vk.z *= fk; vk.w *= fk;
        float4 vkb = make_float4(vk.x * fb, vk.y * fb, vk.z * fb, vk.w * fb);
        float4 vvb = make_float4(vv.x * fb, vv.y * fb, vv.z * fb, vv.w * fb);
        *(float4*)&qs[r][4 * d4] = vq;
        *(float4*)&ks[r][4 * d4] = vk;
        *(float4*)&kb[r][4 * d4] = vkb;
        *(float4*)&vb[r][4 * d4] = vvb;
    }
    __syncthreads();
    // merged: A[i][j] = -(kb_i . kn_j) (j<i), Pl[i][j] = qn_i . kn_j (j<=i)
    for (int rep = 0; rep < 4; ++rep) {
        int idx = t + rep * 256;
        int i = idx >> 5, j = idx & 31;
        float sa = 0.f, sp = 0.f;
        if (j <= i) {
            for (int d4 = 0; d4 < 16; ++d4) {
                float4 kk = *(const float4*)&ks[j][4 * d4];
                float4 qq = *(const float4*)&qs[i][4 * d4];
                float4 bb = *(const float4*)&kb[i][4 * d4];
                sp += qq.x * kk.x + qq.y * kk.y + qq.z * kk.z + qq.w * kk.w;
                sa += bb.x * kk.x + bb.y * kk.y + bb.z * kk.z + bb.w * kk.w;
            }
        }
        A[i][j] = (j < i) ? -sa : 0.f;
        Pl[i][j] = (j <= i) ? sp : 0.f;
    }
    __syncthreads();
    // forward substitution, single wave, columns in registers, no barriers.
    if (t < 64) {
        const int col = t & 31;
        float creg[CH];
        #pragma unroll
        for (int j = 0; j < CH; ++j) creg[j] = A[j][col];
        #pragma unroll
        for (int i = 1; i < CH; ++i) {
            float s = 0.f;
            #pragma unroll
            for (int j = 1; j < i; ++j) s += A[i][j] * creg[j];
            if (col < i) creg[i] += s;
        }
        if (t < 32) {
            #pragma unroll
            for (int j = 0; j < CH; ++j) A[j][col] = creg[j];
        }
    }
    __syncthreads();
    // u = (A+I)@vb -> global row-major (o-region) ; w = (A+I)@kb -> wl (LDS)
    if (t < 128) {
        const int d4 = t & 15;
        const int i0 = (t >> 4) * 4;
        float4 su[4], sw[4];
        #pragma unroll
        for (int ii = 0; ii < 4; ++ii) {
            su[ii] = *(const float4*)&vb[i0 + ii][4 * d4];
            sw[ii] = *(const float4*)&kb[i0 + ii][4 * d4];
        }
        for (int j = 0; j <= i0 + 2; ++j) {
            float4 vv = *(const float4*)&vb[j][4 * d4];
            float4 vk = *(const float4*)&kb[j][4 * d4];
            #pragma unroll
            for (int ii = 0; ii < 4; ++ii) {
                float a = (j < i0 + ii) ? A[i0 + ii][j] : 0.f;
                su[ii].x += a * vv.x; su[ii].y += a * vv.y;
                su[ii].z += a * vv.z; su[ii].w += a * vv.w;
                sw[ii].x += a * vk.x; sw[ii].y += a * vk.y;
                sw[ii].z += a * vk.z; sw[ii].w += a * vk.w;
            }
        }
        #pragma unroll
        for (int ii = 0; ii < 4; ++ii) {
            *(float4*)&u_out[base + (size_t)(i0 + ii) * DD + 4 * d4] = su[ii];
            *(float4*)&wl[i0 + ii][4 * d4] = sw[ii];
        }
    }
    __syncthreads();
    // ---- pack phase: f16 frag stores ----
    {
        const int l = t & 63;
        const int n = l & 15, h = l >> 4;
        const int tw = t >> 6;           // 0..3
        const int mt = tw >> 1, kt = tw & 1;
        const size_t cslot = (size_t)bh * 256 + cc;
        // -w hi/lo A-frags -> over q
        {
            float tmp[8];
            #pragma unroll
            for (int j = 0; j < 8; ++j) tmp[j] = wl[mt * 16 + n][kt * 32 + h * 8 + j];
            split_store(tmp, true, (u16*)q + cslot * 4096 + (size_t)tw * 1024 + l * 16);
        }
        // k^T hi/lo A-frags -> over k   (A[m=d][k=r] = ks[r][d]; tile tw over d)
        {
            float tmp[8];
            #pragma unroll
            for (int j = 0; j < 8; ++j) tmp[j] = ks[h * 8 + j][tw * 16 + n];
            split_store(tmp, false, (u16*)k + cslot * 4096 + (size_t)tw * 1024 + l * 16);
        }
        // q hi A-frags -> ws
        {
            float tmp[8];
            #pragma unroll
            for (int j = 0; j < 8; ++j) tmp[j] = qs[mt * 16 + n][kt * 32 + h * 8 + j];
            hi_store(tmp, qfrag + cslot * 2048 + (size_t)tw * 512 + l * 8);
        }
        // P hi A-frags -> ws (2 tiles)
        if (t < 128) {
            float tmp[8];
            #pragma unroll
            for (int j = 0; j < 8; ++j) tmp[j] = Pl[tw * 16 + n][h * 8 + j];
            hi_store(tmp, pfrag + cslot * 1024 + (size_t)tw * 512 + l * 8);
        }
    }
}

// ---------------------------------------------------------------------------
// Kernel 2: sequential chunk scan. 128 blocks x 1 wave (32 bh x 4 col-groups
// of 16). Zero __syncthreads (single wave); LDS round-trips for C->B layout
// transforms with manual lgkmcnt fences (keeps global prefetch in flight).
// Recurrence math in f16 hi/lo split MFMA (= ~fp32); o-path q/P hi-only.
// blockIdx: bh = x&31, g = x>>5  => the 4 groups of a bh share an XCD (x%8).
// ---------------------------------------------------------------------------
__global__ __launch_bounds__(64) void scan_kernel(
    const u16* __restrict__ wfrag, const u16* __restrict__ ktfrag,
    const u16* __restrict__ qfrag, const u16* __restrict__ pfrag,
    float* __restrict__ uo, float* __restrict__ s_out)
{
    const int bh = blockIdx.x & 31;
    const int g  = blockIdx.x >> 5;
    const int l  = threadIdx.x;
    const int n  = l & 15, h = l >> 4;

    __shared__ __align__(16) float Sc[16 * 76];  // S column-major [n][d], stride 76
    __shared__ __align__(16) float uc[16 * 44];  // u column-major [n][r], stride 44

    const u16* wb = wfrag + (size_t)bh * 256 * 4096;
    const u16* kb = ktfrag + (size_t)bh * 256 * 4096;
    const u16* qb = qfrag + (size_t)bh * 256 * 2048;
    const u16* pb = pfrag + (size_t)bh * 256 * 1024;
    float* ub = uo + (size_t)bh * SEQ * DD + (size_t)g * 16;  // + row*64 + n

    f32x4 Sacc[4];
    const f32x4 fzero = {0.f, 0.f, 0.f, 0.f};
#pragma unroll
    for (int mt = 0; mt < 4; ++mt) Sacc[mt] = fzero;

    // prefetch chunk 0: w frags + u0
    half8 wcur[8];
    float u0cur[8];
#pragma unroll
    for (int tw = 0; tw < 4; ++tw) {
        wcur[tw * 2 + 0] = *(const half8*)(wb + (size_t)tw * 1024 + l * 16);
        wcur[tw * 2 + 1] = *(const half8*)(wb + (size_t)tw * 1024 + l * 16 + 8);
    }
#pragma unroll
    for (int mt = 0; mt < 2; ++mt)
#pragma unroll
        for (int i = 0; i < 4; ++i)
            u0cur[mt * 4 + i] = ub[(size_t)(mt * 16 + h * 4 + i) * 64 + n];

    for (int c = 0; c < NCHUNK; ++c) {
        // ---- dump S (C-frags) to LDS ----
#pragma unroll
        for (int mt = 0; mt < 4; ++mt)
            *(f32x4*)&Sc[n * 76 + mt * 16 + h * 4] = Sacc[mt];

        // ---- early loads for this chunk: kT, q, P (used mid/late chunk) ----
        const u16* kc = kb + (size_t)c * 4096;
        half8 kT[8];
#pragma unroll
        for (int mt = 0; mt < 4; ++mt) {
            kT[mt * 2 + 0] = *(const half8*)(kc + (size_t)mt * 1024 + l * 16);
            kT[mt * 2 + 1] = *(const half8*)(kc + (size_t)mt * 1024 + l * 16 + 8);
        }
        const u16* qc = qb + (size_t)c * 2048;
        half8 qh[4];
#pragma unroll
        for (int tw = 0; tw < 4; ++tw) qh[tw] = *(const half8*)(qc + (size_t)tw * 512 + l * 8);
        const u16* pc = pb + (size_t)c * 1024;
        half8 Ph[2];
#pragma unroll
        for (int mt = 0; mt < 2; ++mt) Ph[mt] = *(const half8*)(pc + (size_t)mt * 512 + l * 8);

        // ---- prefetch next chunk: w frags + u0 ----
        const int cn = (c + 1 < NCHUNK) ? c + 1 : c;
        half8 wn[8];
        float u0n[8];
        {
            const u16* wc = wb + (size_t)cn * 4096;
#pragma unroll
            for (int tw = 0; tw < 4; ++tw) {
                wn[tw * 2 + 0] = *(const half8*)(wc + (size_t)tw * 1024 + l * 16);
                wn[tw * 2 + 1] = *(const half8*)(wc + (size_t)tw * 1024 + l * 16 + 8);
            }
#pragma unroll
            for (int mt = 0; mt < 2; ++mt)
#pragma unroll
                for (int i = 0; i < 4; ++i)
                    u0n[mt * 4 + i] = ub[(size_t)(cn * 32 + mt * 16 + h * 4 + i) * 64 + n];
        }

        // ---- fence, read S as B-frags (f16 hi/lo) ----
        asm volatile("s_waitcnt lgkmcnt(0)" ::: "memory");
        half8 SBhi[2], SBlo[2];
#pragma unroll
        for (int kt = 0; kt < 2; ++kt) {
            f32x4 a = *(const f32x4*)&Sc[n * 76 + kt * 32 + h * 8];
            f32x4 b = *(const f32x4*)&Sc[n * 76 + kt * 32 + h * 8 + 4];
            half8 hi, lo;
#pragma unroll
            for (int j = 0; j < 4; ++j) {
                float x = a[j];
                _Float16 xh = (_Float16)x;
                hi[j] = xh; lo[j] = (_Float16)(x - (float)xh);
            }
#pragma unroll
            for (int j = 0; j < 4; ++j) {
                float x = b[j];
                _Float16 xh = (_Float16)x;
                hi[4 + j] = xh; lo[4 + j] = (_Float16)(x - (float)xh);
            }
            SBhi[kt] = hi; SBlo[kt] = lo;
        }

        // ---- u-phase: u = u0 - w@S  (w stored negated; hi/lo split) ----
        f32x4 accu[2];
#pragma unroll
        for (int mt = 0; mt < 2; ++mt) {
            f32x4 a;
            a[0] = u0cur[mt * 4 + 0]; a[1] = u0cur[mt * 4 + 1];
            a[2] = u0cur[mt * 4 + 2]; a[3] = u0cur[mt * 4 + 3];
#pragma unroll
            for (int kt = 0; kt < 2; ++kt) {
                const int tw = mt * 2 + kt;
                a = MFMA16(wcur[tw * 2 + 0], SBhi[kt], a);
                a = MFMA16(wcur[tw * 2 + 0], SBlo[kt], a);
                a = MFMA16(wcur[tw * 2 + 1], SBhi[kt], a);
            }
            accu[mt] = a;
        }

        // ---- u C->B via LDS ----
#pragma unroll
        for (int mt = 0; mt < 2; ++mt)
            *(f32x4*)&uc[n * 44 + mt * 16 + h * 4] = accu[mt];
        asm volatile("s_waitcnt lgkmcnt(0)" ::: "memory");
        half8 uBhi, uBlo;
        {
            f32x4 a = *(const f32x4*)&uc[n * 44 + h * 8];
            f32x4 b = *(const f32x4*)&uc[n * 44 + h * 8 + 4];
#pragma unroll
            for (int j = 0; j < 4; ++j) {
                float x = a[j];
                _Float16 xh = (_Float16)x;
                uBhi[j] = xh; uBlo[j] = (_Float16)(x - (float)xh);
            }
#pragma unroll
            for (int j = 0; j < 4; ++j) {
                float x = b[j];
                _Float16 xh = (_Float16)x;
                uBhi[4 + j] = xh; uBlo[4 + j] = (_Float16)(x - (float)xh);
            }
        }

        // ---- S update: S += kT @ u (hi/lo split) ----
#pragma unroll
        for (int mt = 0; mt < 4; ++mt) {
            f32x4 a = Sacc[mt];
            a = MFMA16(kT[mt * 2 + 0], uBhi, a);
            a = MFMA16(kT[mt * 2 + 0], uBlo, a);
            a = MFMA16(kT[mt * 2 + 1], uBhi, a);
            Sacc[mt] = a;
        }

        // ---- o = q@S + P@u (hi-only A) ; store over u0 slice ----
#pragma unroll
        for (int mt = 0; mt < 2; ++mt) {
            f32x4 o = fzero;
#pragma unroll
            for (int kt = 0; kt < 2; ++kt) {
                o = MFMA16(qh[mt * 2 + kt], SBhi[kt], o);
                o = MFMA16(qh[mt * 2 + kt], SBlo[kt], o);
            }
            o = MFMA16(Ph[mt], uBhi, o);
            o = MFMA16(Ph[mt], uBlo, o);
#pragma unroll
            for (int i = 0; i < 4; ++i)
                ub[(size_t)(c * 32 + mt * 16 + h * 4 + i) * 64 + n] = o[i];
        }

        // rotate prefetch
#pragma unroll
        for (int z = 0; z < 8; ++z) wcur[z] = wn[z];
#pragma unroll
        for (int z = 0; z < 8; ++z) u0cur[z] = u0n[z];
    }

    // ---- final S -> d_out (b,h,dk,dv) ----
#pragma unroll
    for (int mt = 0; mt < 4; ++mt)
#pragma unroll
        for (int i = 0; i < 4; ++i)
            s_out[(size_t)bh * (DD * DD) + (size_t)(mt * 16 + h * 4 + i) * 64 + g * 16 + n] =
                Sacc[mt][i];
}

extern "C" void kernel_launch(void* const* d_in, const int* in_sizes, int n_in,
                              void* d_out, int out_size, void* d_ws, size_t ws_size,
                              hipStream_t stream) {
    float* q = (float*)d_in[0];
    float* k = (float*)d_in[1];
    const float* v = (const float*)d_in[2];
    const float* beta = (const float*)d_in[3];
    float* out = (float*)d_out;
    float* o_region = out;                          // u0 staging then o (64MB)
    float* s_region = out + (size_t)BH * SEQ * DD;  // final S
    u16* qfr = (u16*)d_ws;                          // 32MB q-hi frags
    u16* pfr = (u16*)((char*)d_ws + 33554432);      // 16MB P-hi frags

    prep_kernel<<<BH * NCHUNK, 256, 0, stream>>>(q, k, v, beta, o_region, qfr, pfr);
    scan_kernel<<<128, 64, 0, stream>>>((const u16*)q, (const u16*)k, qfr, pfr,
                                        o_region, s_region);
}

// Round 4
// 575.950 us; speedup vs baseline: 1.7221x; 1.0569x over previous
//
#include <hip/hip_runtime.h>

#define CH 32      // chunk length
#define DD 64      // dk = dv
#define NCHUNK 256 // chunks per (b,h)
#define SEQ 8192   // sequence length
#define BH 32      // b*h

typedef _Float16 half8 __attribute__((ext_vector_type(8)));
typedef float f32x4 __attribute__((ext_vector_type(4)));
typedef unsigned short u16;

#define MFMA16(a, b, c) __builtin_amdgcn_mfma_f32_16x16x32_f16((a), (b), (c), 0, 0, 0)

// split fp32 -> f16 hi + f16 lo (hi+lo reconstructs to ~2^-21 rel), store frag
__device__ __forceinline__ void split_store(const float* src8, bool neg, u16* dst) {
    half8 hi, lo;
#pragma unroll
    for (int j = 0; j < 8; ++j) {
        float x = neg ? -src8[j] : src8[j];
        _Float16 xh = (_Float16)x;
        hi[j] = xh;
        lo[j] = (_Float16)(x - (float)xh);
    }
    *(half8*)dst = hi;
    *(half8*)(dst + 8) = lo;
}

__device__ __forceinline__ void hi_store(const float* src8, u16* dst) {
    half8 hi;
#pragma unroll
    for (int j = 0; j < 8; ++j) hi[j] = (_Float16)src8[j];
    *(half8*)dst = hi;
}

__device__ __forceinline__ void split8(const float* src8, half8* hi, half8* lo) {
#pragma unroll
    for (int j = 0; j < 8; ++j) {
        float x = src8[j];
        _Float16 xh = (_Float16)x;
        (*hi)[j] = xh;
        (*lo)[j] = (_Float16)(x - (float)xh);
    }
}

// ---------------------------------------------------------------------------
// Kernel 1: per-chunk preprocessing. One block (256 thr = 4 waves) per chunk.
// A/P phase is MFMA f16 hi/lo (one 16x16 tile pair per wave); the rest
// (load/norm, fwd-subst, u/w, pack) unchanged from R3.
// Outputs:
//   d_in[0] (over q): -w as A-frags, f16 hi/lo
//   d_in[1] (over k): k^T as A-frags, f16 hi/lo
//   ws     : q-hi A-frags + P-hi A-frags
//   d_out o-region: u0 fp32 row-major (staging; overwritten with o by scan)
// A-frag layout (16x16x32): lane l supplies A[m=l&15][k=(l>>4)*8+j], j=0..7.
// C-frag layout: lane l holds C[row=(l>>4)*4+i][col=l&15], i=0..3.
// ---------------------------------------------------------------------------
__global__ __launch_bounds__(256) void prep_kernel(
    float* __restrict__ q, float* __restrict__ k,
    const float* __restrict__ v, const float* __restrict__ beta,
    float* __restrict__ u_out, u16* __restrict__ qfrag, u16* __restrict__ pfrag)
{
    const int blk = blockIdx.x;
    const int bh = blk >> 8;
    const int cc = blk & 255;
    const size_t base = ((size_t)bh * SEQ + (size_t)cc * CH) * DD;
    const int t = threadIdx.x;

    __shared__ __align__(16) float qs[CH][68];
    __shared__ __align__(16) float ks[CH][68];
    __shared__ __align__(16) float kb[CH][68];
    __shared__ __align__(16) float vb[CH][68];
    __shared__ __align__(16) float wl[CH][68];
    __shared__ float A[CH][33];
    __shared__ __align__(16) float Pl[CH][36];
    __shared__ float bet[CH];
    __shared__ float rnq[CH];
    __shared__ float rnk[CH];

    if (t < CH) bet[t] = beta[(size_t)bh * SEQ + (size_t)cc * CH + t];
    for (int rep = 0; rep < 2; ++rep) {
        int idx = t + rep * 256;          // float4 index (512 total per array)
        int r = idx >> 4, d4 = idx & 15;
        float4 vq = *(const float4*)&q[base + (size_t)idx * 4];
        float4 vk = *(const float4*)&k[base + (size_t)idx * 4];
        float4 vv = *(const float4*)&v[base + (size_t)idx * 4];
        *(float4*)&qs[r][4 * d4] = vq;
        *(float4*)&ks[r][4 * d4] = vk;
        *(float4*)&vb[r][4 * d4] = vv;
    }
    __syncthreads();
    if (t < CH) {
        float ss = 0.f;
        for (int d4 = 0; d4 < 16; ++d4) {
            float4 x = *(const float4*)&qs[t][4 * d4];
            ss += x.x * x.x + x.y * x.y + x.z * x.z + x.w * x.w;
        }
        rnq[t] = rsqrtf(ss + 1e-6f);
    } else if (t < 2 * CH) {
        int r = t - CH;
        float ss = 0.f;
        for (int d4 = 0; d4 < 16; ++d4) {
            float4 x = *(const float4*)&ks[r][4 * d4];
            ss += x.x * x.x + x.y * x.y + x.z * x.z + x.w * x.w;
        }
        rnk[r] = rsqrtf(ss + 1e-6f);
    }
    __syncthreads();
    for (int rep = 0; rep < 2; ++rep) {
        int idx = t + rep * 256;
        int r = idx >> 4, d4 = idx & 15;
        float4 vq = *(const float4*)&qs[r][4 * d4];
        float4 vk = *(const float4*)&ks[r][4 * d4];
        float4 vv = *(const float4*)&vb[r][4 * d4];
        float fq = rnq[r], fk = rnk[r], fb = bet[r];
        vq.x *= fq; vq.y *= fq; vq.z *= fq; vq.w *= fq;
        vk.x *= fk; vk.y *= fk; vk.z *= fk; vk.w *= fk;
        float4 vkb = make_float4(vk.x * fb, vk.y * fb, vk.z * fb, vk.w * fb);
        float4 vvb = make_float4(vv.x * fb, vv.y * fb, vv.z * fb, vv.w * fb);
        *(float4*)&qs[r][4 * d4] = vq;
        *(float4*)&ks[r][4 * d4] = vk;
        *(float4*)&kb[r][4 * d4] = vkb;
        *(float4*)&vb[r][4 * d4] = vvb;
    }
    __syncthreads();
    // ---- A/P via MFMA f16 hi/lo ----
    // G = kb @ ks^T, Pfull = qs @ ks^T (both 32x32, K=64).
    // wave wv handles tile (mt = wv>>1, nt = wv&1); masked write to A / Pl.
    {
        const int l = t & 63, n = l & 15, h = l >> 4;
        const int wv = t >> 6, mt = wv >> 1, nt = wv & 1;
        half8 kbhi[2], kblo[2], qhi[2], qlo[2], khi[2], klo[2];
#pragma unroll
        for (int kt = 0; kt < 2; ++kt) {
            float a8[8], q8[8], b8[8];
#pragma unroll
            for (int jj = 0; jj < 8; ++jj) {
                a8[jj] = kb[16 * mt + n][32 * kt + 8 * h + jj];
                q8[jj] = qs[16 * mt + n][32 * kt + 8 * h + jj];
                b8[jj] = ks[16 * nt + n][32 * kt + 8 * h + jj];
            }
            split8(a8, &kbhi[kt], &kblo[kt]);
            split8(q8, &qhi[kt], &qlo[kt]);
            split8(b8, &khi[kt], &klo[kt]);
        }
        f32x4 gacc = {0.f, 0.f, 0.f, 0.f};
        f32x4 pacc = {0.f, 0.f, 0.f, 0.f};
#pragma unroll
        for (int kt = 0; kt < 2; ++kt) {
            gacc = MFMA16(kbhi[kt], khi[kt], gacc);
            gacc = MFMA16(kbhi[kt], klo[kt], gacc);
            gacc = MFMA16(kblo[kt], khi[kt], gacc);
            pacc = MFMA16(qhi[kt], khi[kt], pacc);
            pacc = MFMA16(qhi[kt], klo[kt], pacc);
            pacc = MFMA16(qlo[kt], khi[kt], pacc);
        }
#pragma unroll
        for (int i = 0; i < 4; ++i) {
            int ig = 16 * mt + 4 * h + i, jg = 16 * nt + n;
            A[ig][jg] = (jg < ig) ? -gacc[i] : 0.f;
            Pl[ig][jg] = (jg <= ig) ? pacc[i] : 0.f;
        }
    }
    __syncthreads();
    // forward substitution, single wave, columns in registers, no barriers.
    if (t < 64) {
        const int col = t & 31;
        float creg[CH];
        #pragma unroll
        for (int j = 0; j < CH; ++j) creg[j] = A[j][col];
        #pragma unroll
        for (int i = 1; i < CH; ++i) {
            float s = 0.f;
            #pragma unroll
            for (int j = 1; j < i; ++j) s += A[i][j] * creg[j];
            if (col < i) creg[i] += s;
        }
        if (t < 32) {
            #pragma unroll
            for (int j = 0; j < CH; ++j) A[j][col] = creg[j];
        }
    }
    __syncthreads();
    // u = (A+I)@vb -> global row-major (o-region) ; w = (A+I)@kb -> wl (LDS)
    if (t < 128) {
        const int d4 = t & 15;
        const int i0 = (t >> 4) * 4;
        float4 su[4], sw[4];
        #pragma unroll
        for (int ii = 0; ii < 4; ++ii) {
            su[ii] = *(const float4*)&vb[i0 + ii][4 * d4];
            sw[ii] = *(const float4*)&kb[i0 + ii][4 * d4];
        }
        for (int j = 0; j <= i0 + 2; ++j) {
            float4 vv = *(const float4*)&vb[j][4 * d4];
            float4 vk = *(const float4*)&kb[j][4 * d4];
            #pragma unroll
            for (int ii = 0; ii < 4; ++ii) {
                float a = (j < i0 + ii) ? A[i0 + ii][j] : 0.f;
                su[ii].x += a * vv.x; su[ii].y += a * vv.y;
                su[ii].z += a * vv.z; su[ii].w += a * vv.w;
                sw[ii].x += a * vk.x; sw[ii].y += a * vk.y;
                sw[ii].z += a * vk.z; sw[ii].w += a * vk.w;
            }
        }
        #pragma unroll
        for (int ii = 0; ii < 4; ++ii) {
            *(float4*)&u_out[base + (size_t)(i0 + ii) * DD + 4 * d4] = su[ii];
            *(float4*)&wl[i0 + ii][4 * d4] = sw[ii];
        }
    }
    __syncthreads();
    // ---- pack phase: f16 frag stores ----
    {
        const int l = t & 63;
        const int n = l & 15, h = l >> 4;
        const int tw = t >> 6;           // 0..3
        const int mt = tw >> 1, kt = tw & 1;
        const size_t cslot = (size_t)bh * 256 + cc;
        // -w hi/lo A-frags -> over q
        {
            float tmp[8];
            #pragma unroll
            for (int j = 0; j < 8; ++j) tmp[j] = wl[mt * 16 + n][kt * 32 + h * 8 + j];
            split_store(tmp, true, (u16*)q + cslot * 4096 + (size_t)tw * 1024 + l * 16);
        }
        // k^T hi/lo A-frags -> over k   (A[m=d][k=r] = ks[r][d]; tile tw over d)
        {
            float tmp[8];
            #pragma unroll
            for (int j = 0; j < 8; ++j) tmp[j] = ks[h * 8 + j][tw * 16 + n];
            split_store(tmp, false, (u16*)k + cslot * 4096 + (size_t)tw * 1024 + l * 16);
        }
        // q hi A-frags -> ws
        {
            float tmp[8];
            #pragma unroll
            for (int j = 0; j < 8; ++j) tmp[j] = qs[mt * 16 + n][kt * 32 + h * 8 + j];
            hi_store(tmp, qfrag + cslot * 2048 + (size_t)tw * 512 + l * 8);
        }
        // P hi A-frags -> ws (2 tiles)
        if (t < 128) {
            float tmp[8];
            #pragma unroll
            for (int j = 0; j < 8; ++j) tmp[j] = Pl[tw * 16 + n][h * 8 + j];
            hi_store(tmp, pfrag + cslot * 1024 + (size_t)tw * 512 + l * 8);
        }
    }
}

// ---------------------------------------------------------------------------
// Kernel 2: sequential chunk scan. 128 blocks x 1 wave (32 bh x 4 col-groups
// of 16). Zero __syncthreads (single wave); LDS round-trips for C->B layout
// transforms with manual lgkmcnt fences (keeps global prefetch in flight).
// Recurrence math in f16 hi/lo split MFMA (= ~fp32); o-path q/P hi-only.
// ---------------------------------------------------------------------------
__global__ __launch_bounds__(64) void scan_kernel(
    const u16* __restrict__ wfrag, const u16* __restrict__ ktfrag,
    const u16* __restrict__ qfrag, const u16* __restrict__ pfrag,
    float* __restrict__ uo, float* __restrict__ s_out)
{
    const int bh = blockIdx.x & 31;
    const int g  = blockIdx.x >> 5;
    const int l  = threadIdx.x;
    const int n  = l & 15, h = l >> 4;

    __shared__ __align__(16) float Sc[16 * 76];  // S column-major [n][d], stride 76
    __shared__ __align__(16) float uc[16 * 44];  // u column-major [n][r], stride 44

    const u16* wb = wfrag + (size_t)bh * 256 * 4096;
    const u16* kb = ktfrag + (size_t)bh * 256 * 4096;
    const u16* qb = qfrag + (size_t)bh * 256 * 2048;
    const u16* pb = pfrag + (size_t)bh * 256 * 1024;
    float* ub = uo + (size_t)bh * SEQ * DD + (size_t)g * 16;  // + row*64 + n

    f32x4 Sacc[4];
    const f32x4 fzero = {0.f, 0.f, 0.f, 0.f};
#pragma unroll
    for (int mt = 0; mt < 4; ++mt) Sacc[mt] = fzero;

    // prefetch chunk 0: w frags + u0
    half8 wcur[8];
    float u0cur[8];
#pragma unroll
    for (int tw = 0; tw < 4; ++tw) {
        wcur[tw * 2 + 0] = *(const half8*)(wb + (size_t)tw * 1024 + l * 16);
        wcur[tw * 2 + 1] = *(const half8*)(wb + (size_t)tw * 1024 + l * 16 + 8);
    }
#pragma unroll
    for (int mt = 0; mt < 2; ++mt)
#pragma unroll
        for (int i = 0; i < 4; ++i)
            u0cur[mt * 4 + i] = ub[(size_t)(mt * 16 + h * 4 + i) * 64 + n];

    for (int c = 0; c < NCHUNK; ++c) {
        // ---- dump S (C-frags) to LDS ----
#pragma unroll
        for (int mt = 0; mt < 4; ++mt)
            *(f32x4*)&Sc[n * 76 + mt * 16 + h * 4] = Sacc[mt];

        // ---- early loads for this chunk: kT, q, P (used mid/late chunk) ----
        const u16* kc = kb + (size_t)c * 4096;
        half8 kT[8];
#pragma unroll
        for (int mt = 0; mt < 4; ++mt) {
            kT[mt * 2 + 0] = *(const half8*)(kc + (size_t)mt * 1024 + l * 16);
            kT[mt * 2 + 1] = *(const half8*)(kc + (size_t)mt * 1024 + l * 16 + 8);
        }
        const u16* qc = qb + (size_t)c * 2048;
        half8 qh[4];
#pragma unroll
        for (int tw = 0; tw < 4; ++tw) qh[tw] = *(const half8*)(qc + (size_t)tw * 512 + l * 8);
        const u16* pc = pb + (size_t)c * 1024;
        half8 Ph[2];
#pragma unroll
        for (int mt = 0; mt < 2; ++mt) Ph[mt] = *(const half8*)(pc + (size_t)mt * 512 + l * 8);

        // ---- prefetch next chunk: w frags + u0 ----
        const int cn = (c + 1 < NCHUNK) ? c + 1 : c;
        half8 wn[8];
        float u0n[8];
        {
            const u16* wc = wb + (size_t)cn * 4096;
#pragma unroll
            for (int tw = 0; tw < 4; ++tw) {
                wn[tw * 2 + 0] = *(const half8*)(wc + (size_t)tw * 1024 + l * 16);
                wn[tw * 2 + 1] = *(const half8*)(wc + (size_t)tw * 1024 + l * 16 + 8);
            }
#pragma unroll
            for (int mt = 0; mt < 2; ++mt)
#pragma unroll
                for (int i = 0; i < 4; ++i)
                    u0n[mt * 4 + i] = ub[(size_t)(cn * 32 + mt * 16 + h * 4 + i) * 64 + n];
        }

        // ---- fence, read S as B-frags (f16 hi/lo) ----
        asm volatile("s_waitcnt lgkmcnt(0)" ::: "memory");
        half8 SBhi[2], SBlo[2];
#pragma unroll
        for (int kt = 0; kt < 2; ++kt) {
            f32x4 a = *(const f32x4*)&Sc[n * 76 + kt * 32 + h * 8];
            f32x4 b = *(const f32x4*)&Sc[n * 76 + kt * 32 + h * 8 + 4];
            half8 hi, lo;
#pragma unroll
            for (int j = 0; j < 4; ++j) {
                float x = a[j];
                _Float16 xh = (_Float16)x;
                hi[j] = xh; lo[j] = (_Float16)(x - (float)xh);
            }
#pragma unroll
            for (int j = 0; j < 4; ++j) {
                float x = b[j];
                _Float16 xh = (_Float16)x;
                hi[4 + j] = xh; lo[4 + j] = (_Float16)(x - (float)xh);
            }
            SBhi[kt] = hi; SBlo[kt] = lo;
        }

        // ---- u-phase: u = u0 - w@S  (w stored negated; hi/lo split) ----
        f32x4 accu[2];
#pragma unroll
        for (int mt = 0; mt < 2; ++mt) {
            f32x4 a;
            a[0] = u0cur[mt * 4 + 0]; a[1] = u0cur[mt * 4 + 1];
            a[2] = u0cur[mt * 4 + 2]; a[3] = u0cur[mt * 4 + 3];
#pragma unroll
            for (int kt = 0; kt < 2; ++kt) {
                const int tw = mt * 2 + kt;
                a = MFMA16(wcur[tw * 2 + 0], SBhi[kt], a);
                a = MFMA16(wcur[tw * 2 + 0], SBlo[kt], a);
                a = MFMA16(wcur[tw * 2 + 1], SBhi[kt], a);
            }
            accu[mt] = a;
        }

        // ---- u C->B via LDS ----
#pragma unroll
        for (int mt = 0; mt < 2; ++mt)
            *(f32x4*)&uc[n * 44 + mt * 16 + h * 4] = accu[mt];
        asm volatile("s_waitcnt lgkmcnt(0)" ::: "memory");
        half8 uBhi, uBlo;
        {
            f32x4 a = *(const f32x4*)&uc[n * 44 + h * 8];
            f32x4 b = *(const f32x4*)&uc[n * 44 + h * 8 + 4];
#pragma unroll
            for (int j = 0; j < 4; ++j) {
                float x = a[j];
                _Float16 xh = (_Float16)x;
                uBhi[j] = xh; uBlo[j] = (_Float16)(x - (float)xh);
            }
#pragma unroll
            for (int j = 0; j < 4; ++j) {
                float x = b[j];
                _Float16 xh = (_Float16)x;
                uBhi[4 + j] = xh; uBlo[4 + j] = (_Float16)(x - (float)xh);
            }
        }

        // ---- S update: S += kT @ u (hi/lo split) ----
#pragma unroll
        for (int mt = 0; mt < 4; ++mt) {
            f32x4 a = Sacc[mt];
            a = MFMA16(kT[mt * 2 + 0], uBhi, a);
            a = MFMA16(kT[mt * 2 + 0], uBlo, a);
            a = MFMA16(kT[mt * 2 + 1], uBhi, a);
            Sacc[mt] = a;
        }

        // ---- o = q@S + P@u (hi-only A) ; store over u0 slice ----
#pragma unroll
        for (int mt = 0; mt < 2; ++mt) {
            f32x4 o = fzero;
#pragma unroll
            for (int kt = 0; kt < 2; ++kt) {
                o = MFMA16(qh[mt * 2 + kt], SBhi[kt], o);
                o = MFMA16(qh[mt * 2 + kt], SBlo[kt], o);
            }
            o = MFMA16(Ph[mt], uBhi, o);
            o = MFMA16(Ph[mt], uBlo, o);
#pragma unroll
            for (int i = 0; i < 4; ++i)
                ub[(size_t)(c * 32 + mt * 16 + h * 4 + i) * 64 + n] = o[i];
        }

        // rotate prefetch
#pragma unroll
        for (int z = 0; z < 8; ++z) wcur[z] = wn[z];
#pragma unroll
        for (int z = 0; z < 8; ++z) u0cur[z] = u0n[z];
    }

    // ---- final S -> d_out (b,h,dk,dv) ----
#pragma unroll
    for (int mt = 0; mt < 4; ++mt)
#pragma unroll
        for (int i = 0; i < 4; ++i)
            s_out[(size_t)bh * (DD * DD) + (size_t)(mt * 16 + h * 4 + i) * 64 + g * 16 + n] =
                Sacc[mt][i];
}

extern "C" void kernel_launch(void* const* d_in, const int* in_sizes, int n_in,
                              void* d_out, int out_size, void* d_ws, size_t ws_size,
                              hipStream_t stream) {
    float* q = (float*)d_in[0];
    float* k = (float*)d_in[1];
    const float* v = (const float*)d_in[2];
    const float* beta = (const float*)d_in[3];
    float* out = (float*)d_out;
    float* o_region = out;                          // u0 staging then o (64MB)
    float* s_region = out + (size_t)BH * SEQ * DD;  // final S
    u16* qfr = (u16*)d_ws;                          // 32MB q-hi frags
    u16* pfr = (u16*)((char*)d_ws + 33554432);      // 16MB P-hi frags

    prep_kernel<<<BH * NCHUNK, 256, 0, stream>>>(q, k, v, beta, o_region, qfr, pfr);
    scan_kernel<<<128, 64, 0, stream>>>((const u16*)q, (const u16*)k, qfr, pfr,
                                        o_region, s_region);
}